// Round 7
// baseline (214.112 us; speedup 1.0000x reference)
//
#include <hip/hip_runtime.h>

// VectorQuantizer: latents (16,128,64,64) f32, codebook (1024,128) f32.
// out[b,d,h,w] = codebook[argmin_k fl(fl(x2 - 2*dot(x,e_k)) + e2_k)][d]
//
// MFMA bf16 scoring + exact fp32 rescue:
//  phase 1: 16x16x32 bf16 MFMA scores (fp32 acc) -> per-px min in the
//           x2-free domain s' = fl(e2_k - 2*C_k).
//  phase 2: recompute s'; candidates = { k : s' <= min' + 2*M[px] },
//           M = 2e-4*sqrt(x2) + 2.5e-4  (validated R3-R6, absmax 3.8e-6).
//  rescue:  exact fp32 serial ascending-d fmaf chain on ~2 cands/px;
//           lex (t3,k) u64 atomicMin keeps np first-index tie-break.
//
// Round-10 (ABLATION round -- pre-committed falsifier fired: 3 consecutive
// pipelining designs all regressed; latency model discredited; measure).
//  - vq_main_kernel: best-of-all-rounds hybrid, NO pipelining:
//    R4 dual staging (fp32 xl for x2/rescue + swizzled bf16 xbf for
//    conflict-free A-build; cand/bfminw alias dead xbf), R2 single-buffer
//    direct-global B loop, 1-fma epilogue, NEW: e2 rotating one-iter-ahead
//    scalar prefetch (removes a dependent global load from the critical
//    path of every c-iteration; static rotation, no dynamic indexing).
//  - vq_probe_kernel: identical front + phase1 + reduce/thresh, result
//    asm-sinked (rule 17), no global writes. Full grid, so its duration
//    decomposes main via: probe = dur_us - main(rocprof) - ~63us overhead.
//  Launch: prep -> main (real output; comparable to all prior rounds)
//          -> probe (diagnostic).

typedef __attribute__((ext_vector_type(8))) short short8;
typedef __attribute__((ext_vector_type(4))) float f32x4;

#define VQ_D 128
#define VQ_K 1024
#define VQ_HW 4096
#define CAND_CAP 4096

__device__ inline unsigned short f2bf(float f) {   // RNE fp32->bf16
    unsigned u = __float_as_uint(f);
    return (unsigned short)((u + 0x7FFFu + ((u >> 16) & 1u)) >> 16);
}

__global__ __launch_bounds__(256)
void vq_prep_kernel(const float* __restrict__ cb, unsigned short* __restrict__ cbbf,
                    float* __restrict__ e2) {
    __shared__ __align__(16) float rows[32][132];
    const int tid = threadIdx.x;
    const int k0  = blockIdx.x << 5;                 // 32 codes/block, grid=32
    const float4* s4 = (const float4*)(cb + (size_t)k0 * VQ_D);
    ushort4* d4 = (ushort4*)(cbbf + (size_t)k0 * VQ_D);
    #pragma unroll
    for (int i = 0; i < 4; ++i) {                    // 1024 float4 per block
        const int idx = i * 256 + tid;               // coalesced
        const float4 v = s4[idx];
        const int r  = idx >> 5;
        const int c4 = (idx & 31) << 2;
        *(float4*)(&rows[r][c4]) = v;
        ushort4 p;
        p.x = f2bf(v.x); p.y = f2bf(v.y); p.z = f2bf(v.z); p.w = f2bf(v.w);
        d4[idx] = p;
    }
    __syncthreads();
    if (tid < 32) {                                  // serial chain, same order
        float s = 0.f;
        #pragma unroll
        for (int d = 0; d < VQ_D; ++d) {
            const float v = rows[tid][d];
            s = fmaf(v, v, s);
        }
        e2[k0 + tid] = s;
    }
}

// ---- shared building blocks -----------------------------------------------
#define VQ_PREAMBLE()                                                            \
    const int tid  = threadIdx.x;                                                \
    const int lane = tid & 63;                                                   \
    const int wave = __builtin_amdgcn_readfirstlane(tid >> 6);                   \
    const int quad = lane >> 4;                                                  \
    const int mm   = lane & 15;                                                  \
    const int blk  = blockIdx.x;                                                 \
    const int b    = blk >> 6;                                                   \
    const int hw0  = (blk & 63) << 6;                                            \
    const float* xg = latents + (size_t)b * VQ_D * VQ_HW + hw0;                  \
    (void)lane;

// stage both: fp32 xl[d][px] (float4) and bf16 xbf[px][d] (swizzled b32)
#define VQ_STAGE_X()                                                             \
    {                                                                            \
        const int px4 = (tid & 15) << 2;                                         \
        const int db  = (tid >> 4) << 3;                                         \
        _Pragma("unroll")                                                        \
        for (int dp = 0; dp < 4; ++dp) {                                         \
            const int d0 = db + dp * 2;                                          \
            const float4 va = *(const float4*)(xg + (size_t)d0 * VQ_HW + px4);   \
            const float4 vb = *(const float4*)(xg + (size_t)(d0 + 1) * VQ_HW + px4); \
            *(float4*)(xl + d0 * 64 + px4)       = va;                           \
            *(float4*)(xl + (d0 + 1) * 64 + px4) = vb;                           \
            const float* fa = (const float*)&va;                                 \
            const float* fb = (const float*)&vb;                                 \
            _Pragma("unroll")                                                    \
            for (int i = 0; i < 4; ++i) {                                        \
                const int px = px4 + i;                                          \
                const unsigned lo = f2bf(fa[i]);                                 \
                const unsigned hi = f2bf(fb[i]);                                 \
                const int slot = (d0 >> 3) ^ (px & 15);                          \
                *(unsigned*)((char*)xbf + px * 256 + slot * 16 + (d0 & 7) * 2) = \
                    lo | (hi << 16);                                             \
            }                                                                    \
        }                                                                        \
    }

#define VQ_ABUILD()                                                              \
    short8 A[16];                                                                \
    _Pragma("unroll")                                                            \
    for (int p = 0; p < 4; ++p) {                                                \
        const int px = p * 16 + mm;                                              \
        _Pragma("unroll")                                                        \
        for (int t = 0; t < 4; ++t) {                                            \
            const int slot = (t * 4 + quad) ^ mm;                                \
            A[p * 4 + t] = *(const short8*)((const char*)xbf + px * 256 + slot * 16); \
        }                                                                        \
    }

#define VQ_X2()                                                                  \
    if (tid < 64) {                                                              \
        float s = 0.f;                                                           \
        _Pragma("unroll")                                                        \
        for (int d = 0; d < VQ_D; ++d) {                                         \
            const float v = xl[d * 64 + tid];                                    \
            s = fmaf(v, v, s);                                                   \
        }                                                                        \
        x2s[tid] = s;                                                            \
    }

#define VQ_MFMA(Bv)                                                              \
    f32x4 Cm[4] = {{0.f,0.f,0.f,0.f},{0.f,0.f,0.f,0.f},                          \
                   {0.f,0.f,0.f,0.f},{0.f,0.f,0.f,0.f}};                         \
    _Pragma("unroll")                                                            \
    for (int t = 0; t < 4; ++t)                                                  \
        _Pragma("unroll")                                                        \
        for (int p = 0; p < 4; ++p)                                              \
            Cm[p] = __builtin_amdgcn_mfma_f32_16x16x32_bf16(                     \
                        A[p * 4 + t], Bv[t], Cm[p], 0, 0, 0);

#define VQ_REDUCE_THRESH()                                                       \
    _Pragma("unroll")                                                            \
    for (int i = 0; i < 16; ++i) {                                               \
        float v = bmin[i];                                                       \
        v = fminf(v, __shfl_xor(v, 1));                                          \
        v = fminf(v, __shfl_xor(v, 2));                                          \
        v = fminf(v, __shfl_xor(v, 4));                                          \
        v = fminf(v, __shfl_xor(v, 8));                                          \
        bmin[i] = v;                                                             \
    }                                                                            \
    if (mm == 0) {                                                               \
        _Pragma("unroll")                                                        \
        for (int p = 0; p < 4; ++p)                                              \
            _Pragma("unroll")                                                    \
            for (int r = 0; r < 4; ++r)                                          \
                bfminw[wave][p * 16 + quad * 4 + r] = bmin[p * 4 + r];           \
    }                                                                            \
    __syncthreads();                                                             \
    if (tid < 64) {                                                              \
        const float mn = fminf(fminf(bfminw[0][tid], bfminw[1][tid]),            \
                               fminf(bfminw[2][tid], bfminw[3][tid]));           \
        const float M = 2.0e-4f * sqrtf(x2s[tid]) + 2.5e-4f;                     \
        threshs[tid] = mn + 2.0f * M;                                            \
    }                                                                            \
    __syncthreads();

// ---- the candidate --------------------------------------------------------
__global__ __launch_bounds__(256)
void vq_main_kernel(const float* __restrict__ latents,
                    const float* __restrict__ cb,
                    const unsigned short* __restrict__ cbbf,
                    const float* __restrict__ e2,
                    float* __restrict__ out) {
    __shared__ __align__(16) float xl[VQ_D * 64];            // [d][px] 32 KB
    __shared__ __align__(16) unsigned short xbf[64 * 128];   // 16 KB, dies at A-build
    __shared__ float x2s[64];
    __shared__ float threshs[64];
    __shared__ unsigned long long fkey[64];
    __shared__ int ncand;
    unsigned int* cand = (unsigned int*)xbf;                 // alias (post-thresh)
    float (*bfminw)[64] = (float (*)[64])xbf;                // alias (post-A-build)

    VQ_PREAMBLE()
    VQ_STAGE_X()
    if (tid == 0) ncand = 0;
    if (tid < 64) fkey[tid] = ~0ULL;
    __syncthreads();   // xl + xbf staged

    VQ_ABUILD()        // A in 64 VGPRs, conflict-free swizzled reads
    VQ_X2()            // serial ascending-d chain from xl (exact fp32)
    __syncthreads();   // xbf DEAD; x2s ready; aliasing legal

    const float* e2g = e2 + wave * 256 + mm;
    const unsigned short* bbase = cbbf + (size_t)(wave * 256 + mm) * VQ_D + quad * 8;

    // ---- phase 1: single-buffered B, e2 rotated one-iter-ahead ----
    float bmin[16];
    #pragma unroll
    for (int i = 0; i < 16; ++i) bmin[i] = 1e30f;
    {
        float e2n = e2g[0];
        #pragma unroll 1
        for (int c = 0; c < 16; ++c) {
            short8 B[4];
            #pragma unroll
            for (int t = 0; t < 4; ++t)
                B[t] = *(const short8*)(bbase + (size_t)c * 16 * VQ_D + t * 32);
            const float e2c = e2n;
            if (c < 15) e2n = e2g[(c + 1) * 16];   // off critical path
            VQ_MFMA(B)
            #pragma unroll
            for (int p = 0; p < 4; ++p)
                #pragma unroll
                for (int r = 0; r < 4; ++r) {
                    const float s = fmaf(-2.0f, Cm[p][r], e2c);
                    bmin[p * 4 + r] = fminf(bmin[p * 4 + r], s);
                }
        }
    }

    VQ_REDUCE_THRESH()

    float thr[16];
    #pragma unroll
    for (int p = 0; p < 4; ++p)
        #pragma unroll
        for (int r = 0; r < 4; ++r)
            thr[p * 4 + r] = threshs[p * 16 + quad * 4 + r];

    // ---- phase 2: recompute s', collect candidates ----
    {
        float e2n = e2g[0];
        #pragma unroll 1
        for (int c = 0; c < 16; ++c) {
            short8 B[4];
            #pragma unroll
            for (int t = 0; t < 4; ++t)
                B[t] = *(const short8*)(bbase + (size_t)c * 16 * VQ_D + t * 32);
            const float e2c = e2n;
            if (c < 15) e2n = e2g[(c + 1) * 16];
            VQ_MFMA(B)
            #pragma unroll
            for (int p = 0; p < 4; ++p)
                #pragma unroll
                for (int r = 0; r < 4; ++r) {
                    const float s = fmaf(-2.0f, Cm[p][r], e2c);
                    if (s <= thr[p * 4 + r]) {
                        const int idx = atomicAdd(&ncand, 1);
                        if (idx < CAND_CAP) {
                            const int px   = p * 16 + quad * 4 + r;
                            const int code = wave * 256 + c * 16 + mm;
                            cand[idx] = ((unsigned)px << 16) | (unsigned)code;
                        }
                    }
                }
        }
    }
    __syncthreads();

    // ---- rescue: exact fp32 serial chain from xl (bank-free) ----
    const int nc = ncand < CAND_CAP ? ncand : CAND_CAP;
    for (int i = tid; i < nc; i += 256) {
        const unsigned pc = cand[i];
        const int px = (int)(pc >> 16);
        const int k  = (int)(pc & 0xFFFFu);
        const float* crow = cb + (size_t)k * VQ_D;
        float dot = 0.f;
        #pragma unroll
        for (int q = 0; q < 32; ++q) {
            const float4 cv = *(const float4*)(crow + q * 4);
            dot = fmaf(xl[(q * 4 + 0) * 64 + px], cv.x, dot);
            dot = fmaf(xl[(q * 4 + 1) * 64 + px], cv.y, dot);
            dot = fmaf(xl[(q * 4 + 2) * 64 + px], cv.z, dot);
            dot = fmaf(xl[(q * 4 + 3) * 64 + px], cv.w, dot);
        }
        const float t3 = (x2s[px] - 2.0f * dot) + e2[k];
        const unsigned long long key =
            ((unsigned long long)__float_as_uint(t3) << 32) | (unsigned)k;
        atomicMin(&fkey[px], key);
    }
    __syncthreads();

    // ---- writeback: vectorized codebook reads, nontemporal out stores ----
    {
        const int px = tid & 63;
        const int dh = tid >> 6;
        const int fb = (int)(fkey[px] & 0xFFFFFFFFULL);
        const float* crow = cb + (size_t)fb * VQ_D + dh * 32;
        float* og = out + (size_t)b * VQ_D * VQ_HW + hw0;
        #pragma unroll
        for (int j = 0; j < 8; ++j) {
            const float4 cv = *(const float4*)(crow + j * 4);
            const int d = dh * 32 + j * 4;
            __builtin_nontemporal_store(cv.x, &og[(size_t)(d + 0) * VQ_HW + px]);
            __builtin_nontemporal_store(cv.y, &og[(size_t)(d + 1) * VQ_HW + px]);
            __builtin_nontemporal_store(cv.z, &og[(size_t)(d + 2) * VQ_HW + px]);
            __builtin_nontemporal_store(cv.w, &og[(size_t)(d + 3) * VQ_HW + px]);
        }
    }
}

// ---- diagnostic probe: front + phase1 + reduce/thresh, sinked -------------
__global__ __launch_bounds__(256)
void vq_probe_kernel(const float* __restrict__ latents,
                     const unsigned short* __restrict__ cbbf,
                     const float* __restrict__ e2) {
    __shared__ __align__(16) float xl[VQ_D * 64];
    __shared__ __align__(16) unsigned short xbf[64 * 128];
    __shared__ float x2s[64];
    __shared__ float threshs[64];
    float (*bfminw)[64] = (float (*)[64])xbf;

    VQ_PREAMBLE()
    VQ_STAGE_X()
    __syncthreads();

    VQ_ABUILD()
    VQ_X2()
    __syncthreads();

    const float* e2g = e2 + wave * 256 + mm;
    const unsigned short* bbase = cbbf + (size_t)(wave * 256 + mm) * VQ_D + quad * 8;

    float bmin[16];
    #pragma unroll
    for (int i = 0; i < 16; ++i) bmin[i] = 1e30f;
    {
        float e2n = e2g[0];
        #pragma unroll 1
        for (int c = 0; c < 16; ++c) {
            short8 B[4];
            #pragma unroll
            for (int t = 0; t < 4; ++t)
                B[t] = *(const short8*)(bbase + (size_t)c * 16 * VQ_D + t * 32);
            const float e2c = e2n;
            if (c < 15) e2n = e2g[(c + 1) * 16];
            VQ_MFMA(B)
            #pragma unroll
            for (int p = 0; p < 4; ++p)
                #pragma unroll
                for (int r = 0; r < 4; ++r) {
                    const float s = fmaf(-2.0f, Cm[p][r], e2c);
                    bmin[p * 4 + r] = fminf(bmin[p * 4 + r], s);
                }
        }
    }

    VQ_REDUCE_THRESH()

    // keep the entire chain live (rule 17): depends on all bfminw + x2s.
    const float tv = threshs[(tid + 17) & 63];
    asm volatile("" :: "v"(tv));
}

extern "C" void kernel_launch(void* const* d_in, const int* in_sizes, int n_in,
                              void* d_out, int out_size, void* d_ws, size_t ws_size,
                              hipStream_t stream) {
    const float* latents = (const float*)d_in[0];
    const float* cb      = (const float*)d_in[1];
    unsigned short* cbbf = (unsigned short*)d_ws;              // 256 KB
    float* e2            = (float*)((char*)d_ws + 262144);     // 4 KB
    float* out           = (float*)d_out;

    vq_prep_kernel<<<dim3(32), dim3(256), 0, stream>>>(cb, cbbf, e2);
    vq_main_kernel<<<dim3(1024), dim3(256), 0, stream>>>(latents, cb, cbbf, e2, out);
    vq_probe_kernel<<<dim3(1024), dim3(256), 0, stream>>>(latents, cbbf, e2);
}

// Round 9
// 188.262 us; speedup vs baseline: 1.1373x; 1.1373x over previous
//
#include <hip/hip_runtime.h>

// VectorQuantizer: latents (16,128,64,64) f32, codebook (1024,128) f32.
// out[b,d,h,w] = codebook[argmin_k fl(fl(x2 - 2*dot(x,e_k)) + e2_k)][d]
//
// SINGLE-SWEEP MFMA bf16 scoring + exact fp32 rescue (round 8b; R7's probe
// showed phase1~32us, phase2~33us, tail~28us of main=107 -> delete phase 2):
//  sweep:   16x16x32 bf16 MFMA scores s' = fl(e2_k - 2*C) (x2-free domain,
//           validated R3-R7). A shared per-px running min smin[64] lives in
//           LDS as order-preserving u32 (enc: u^(0x80000000|(int)u>>31));
//           rare record-breaking ds_min_u32 atomics keep it tight.
//           Candidates: s <= dec(smin[px]) + 2Mmax collected as u64
//           (enc_score | px<<10 | code). SUPERSET proof: dec(smin)>=final
//           min and 2Mmax>=2M[px] (Mmax from the block's true x2 max, no
//           input assumption) -> never misses an exact candidate.
//  exact:   post-sweep, smin IS the exact bf16 min (enc lossless);
//           thr[px] = min + 2*(2e-4*sqrt(x2)+2.5e-4) as always; candidates
//           refiltered by enc(s)<=enc(thr) (equiv s<=thr) before rescue.
//  iter-0:  no threshold exists yet -> replayed once post-thr (1/16 sweep).
//  overflow: ncand>CAP (~500 expected vs 2048 cap) -> block-local full
//           exact replay. Correctness-total either way.
//  rescue:  exact fp32 serial ascending-d fmaf chain from xl (unchanged);
//           lex (t3,k) u64 atomicMin keeps np first-index tie-break.
//  writeback: f32x4 nt stores (R8 fix: __builtin_nontemporal_store needs a
//           true vector type, not HIP_vector_type float4).

typedef __attribute__((ext_vector_type(8))) short short8;
typedef __attribute__((ext_vector_type(4))) float f32x4;

#define VQ_D 128
#define VQ_K 1024
#define VQ_HW 4096
#define CAND_CAP 2048

__device__ inline unsigned short f2bf(float f) {   // RNE fp32->bf16
    unsigned u = __float_as_uint(f);
    return (unsigned short)((u + 0x7FFFu + ((u >> 16) & 1u)) >> 16);
}
__device__ inline unsigned f2ord(float f) {        // order-preserving encode
    const unsigned u = __float_as_uint(f);
    return u ^ (0x80000000u | (unsigned)((int)u >> 31));
}
__device__ inline float ord2f(unsigned e) {        // exact inverse
    const unsigned u = (e & 0x80000000u) ? (e ^ 0x80000000u) : ~e;
    return __uint_as_float(u);
}

__global__ __launch_bounds__(256)
void vq_prep_kernel(const float* __restrict__ cb, unsigned short* __restrict__ cbbf,
                    float* __restrict__ e2) {
    __shared__ __align__(16) float rows[32][132];
    const int tid = threadIdx.x;
    const int k0  = blockIdx.x << 5;                 // 32 codes/block, grid=32
    const float4* s4 = (const float4*)(cb + (size_t)k0 * VQ_D);
    ushort4* d4 = (ushort4*)(cbbf + (size_t)k0 * VQ_D);
    #pragma unroll
    for (int i = 0; i < 4; ++i) {                    // 1024 float4 per block
        const int idx = i * 256 + tid;               // coalesced
        const float4 v = s4[idx];
        const int r  = idx >> 5;
        const int c4 = (idx & 31) << 2;
        *(float4*)(&rows[r][c4]) = v;
        ushort4 p;
        p.x = f2bf(v.x); p.y = f2bf(v.y); p.z = f2bf(v.z); p.w = f2bf(v.w);
        d4[idx] = p;
    }
    __syncthreads();
    if (tid < 32) {                                  // serial chain, same order
        float s = 0.f;
        #pragma unroll
        for (int d = 0; d < VQ_D; ++d) {
            const float v = rows[tid][d];
            s = fmaf(v, v, s);
        }
        e2[k0 + tid] = s;
    }
}

#define VQ_MFMA(Bv)                                                              \
    f32x4 Cm[4] = {{0.f,0.f,0.f,0.f},{0.f,0.f,0.f,0.f},                          \
                   {0.f,0.f,0.f,0.f},{0.f,0.f,0.f,0.f}};                         \
    _Pragma("unroll")                                                            \
    for (int t = 0; t < 4; ++t)                                                  \
        _Pragma("unroll")                                                        \
        for (int p = 0; p < 4; ++p)                                              \
            Cm[p] = __builtin_amdgcn_mfma_f32_16x16x32_bf16(                     \
                        A[p * 4 + t], Bv[t], Cm[p], 0, 0, 0);

#define VQ_LDB(c_)                                                               \
    short8 B[4];                                                                 \
    _Pragma("unroll")                                                            \
    for (int t = 0; t < 4; ++t)                                                  \
        B[t] = *(const short8*)(bbase + (size_t)(c_) * 16 * VQ_D + t * 32);

// exact-threshold emit for one code group (used by iter-0 replay + fallback)
#define VQ_EMIT_EXACT(c_)                                                        \
    {                                                                            \
        VQ_LDB(c_)                                                               \
        const float e2c = e2g[(c_) * 16];                                        \
        VQ_MFMA(B)                                                               \
        _Pragma("unroll")                                                        \
        for (int p = 0; p < 4; ++p)                                              \
            _Pragma("unroll")                                                    \
            for (int r = 0; r < 4; ++r) {                                        \
                const float s = fmaf(-2.0f, Cm[p][r], e2c);                      \
                const int px = p * 16 + quad * 4 + r;                            \
                const unsigned eu = f2ord(s);                                    \
                if (eu <= encThr[px]) {                                          \
                    const int idx = atomicAdd(&ncand, 1);                        \
                    if (idx < CAND_CAP)                                          \
                        cand[idx] = ((unsigned long long)eu << 32) |             \
                                    (unsigned)(px << 10) |                       \
                                    (unsigned)(wave * 256 + (c_) * 16 + mm);     \
                }                                                                \
            }                                                                    \
    }

__global__ __launch_bounds__(256)
void vq_main_kernel(const float* __restrict__ latents,
                    const float* __restrict__ cb,
                    const unsigned short* __restrict__ cbbf,
                    const float* __restrict__ e2,
                    float* __restrict__ out) {
    __shared__ __align__(16) float xl[VQ_D * 64];            // [d][px] 32 KB
    __shared__ __align__(16) unsigned short xbf[64 * 128];   // 16 KB, dies at A-build
    __shared__ float x2s[64];
    __shared__ unsigned smin[64];                            // enc'd running min
    __shared__ unsigned encThr[64];
    __shared__ unsigned long long fkey[64];
    __shared__ float twoMbS;
    __shared__ int ncand;
    unsigned long long* cand = (unsigned long long*)xbf;     // [2048] u64, 16 KB

    const int tid  = threadIdx.x;
    const int lane = tid & 63;
    const int wave = __builtin_amdgcn_readfirstlane(tid >> 6);
    const int quad = lane >> 4;
    const int mm   = lane & 15;
    const int blk  = blockIdx.x;
    const int b    = blk >> 6;
    const int hw0  = (blk & 63) << 6;

    const float* xg = latents + (size_t)b * VQ_D * VQ_HW + hw0;

    // ---- stage: fp32 xl[d][px] + swizzled bf16 xbf[px][d] ----
    {
        const int px4 = (tid & 15) << 2;
        const int db  = (tid >> 4) << 3;
        #pragma unroll
        for (int dp = 0; dp < 4; ++dp) {
            const int d0 = db + dp * 2;
            const float4 va = *(const float4*)(xg + (size_t)d0 * VQ_HW + px4);
            const float4 vb = *(const float4*)(xg + (size_t)(d0 + 1) * VQ_HW + px4);
            *(float4*)(xl + d0 * 64 + px4)       = va;
            *(float4*)(xl + (d0 + 1) * 64 + px4) = vb;
            const float* fa = (const float*)&va;
            const float* fb = (const float*)&vb;
            #pragma unroll
            for (int i = 0; i < 4; ++i) {
                const int px = px4 + i;
                const unsigned lo = f2bf(fa[i]);
                const unsigned hi = f2bf(fb[i]);
                const int slot = (d0 >> 3) ^ (px & 15);
                *(unsigned*)((char*)xbf + px * 256 + slot * 16 + (d0 & 7) * 2) =
                    lo | (hi << 16);
            }
        }
    }
    if (tid == 0) ncand = 0;
    if (tid < 64) { fkey[tid] = ~0ULL; smin[tid] = 0xFF800000u; }  // enc(+inf)
    __syncthreads();   // xl + xbf staged

    // ---- A fragments (64 VGPR), conflict-free swizzled reads ----
    short8 A[16];
    #pragma unroll
    for (int p = 0; p < 4; ++p) {
        const int px = p * 16 + mm;
        #pragma unroll
        for (int t = 0; t < 4; ++t) {
            const int slot = (t * 4 + quad) ^ mm;
            A[p * 4 + t] = *(const short8*)((const char*)xbf + px * 256 + slot * 16);
        }
    }

    // x2 (exact serial chain) + block x2-max -> 2*Mmax (wave 0)
    if (tid < 64) {
        float s = 0.f;
        #pragma unroll
        for (int d = 0; d < VQ_D; ++d) {
            const float v = xl[d * 64 + tid];
            s = fmaf(v, v, s);
        }
        x2s[tid] = s;
        float mx = s;
        #pragma unroll
        for (int off = 1; off < 64; off <<= 1)
            mx = fmaxf(mx, __shfl_xor(mx, off));
        if (tid == 0) twoMbS = 2.0f * (2.0e-4f * sqrtf(mx) + 2.5e-4f);
    }
    __syncthreads();   // xbf DEAD (A in regs); smin/x2/twoMb ready

    const float twoMb = twoMbS;
    const float* e2g = e2 + wave * 256 + mm;
    const unsigned short* bbase = cbbf + (size_t)(wave * 256 + mm) * VQ_D + quad * 8;

    // ---- THE sweep: score, track shared running min, collect loose ----
    {
        float e2n = e2g[0];
        #pragma unroll 1
        for (int cc = 0; cc < 16; ++cc) {
            VQ_LDB(cc)
            const float e2c = e2n;
            if (cc < 15) e2n = e2g[(cc + 1) * 16];
            VQ_MFMA(B)
            #pragma unroll
            for (int p = 0; p < 4; ++p)
                #pragma unroll
                for (int r = 0; r < 4; ++r) {
                    const float s = fmaf(-2.0f, Cm[p][r], e2c);
                    const int px = p * 16 + quad * 4 + r;
                    const unsigned srd = smin[px];
                    const float mnv = ord2f(srd);
                    if (s <= mnv + twoMb) {          // rare (records + near)
                        if (s < mnv) atomicMin(&smin[px], f2ord(s));
                        if (cc > 0) {                // iter 0 replayed later
                            const int idx = atomicAdd(&ncand, 1);
                            if (idx < CAND_CAP)
                                cand[idx] =
                                    ((unsigned long long)f2ord(s) << 32) |
                                    (unsigned)(px << 10) |
                                    (unsigned)(wave * 256 + cc * 16 + mm);
                        }
                    }
                }
        }
    }
    __syncthreads();   // smin final = exact bf16 min per px

    if (tid < 64) {
        const float mn = ord2f(smin[tid]);
        const float M  = 2.0e-4f * sqrtf(x2s[tid]) + 2.5e-4f;
        encThr[tid] = f2ord(mn + 2.0f * M);
    }
    __syncthreads();

    // iter-0 backlog: exact-threshold replay of code group 0
    VQ_EMIT_EXACT(0)
    __syncthreads();
    int ncv = ncand;
    __syncthreads();
    if (ncv > CAND_CAP) {                            // overflow insurance
        if (tid == 0) ncand = 0;
        __syncthreads();
        #pragma unroll 1
        for (int cc = 0; cc < 16; ++cc) VQ_EMIT_EXACT(cc)
        __syncthreads();
        ncv = ncand;
    }
    const int nc = ncv < CAND_CAP ? ncv : CAND_CAP;

    // ---- rescue: exact refilter + exact fp32 serial chain from xl ----
    for (int i = tid; i < nc; i += 256) {
        const unsigned long long e = cand[i];
        const unsigned eu = (unsigned)(e >> 32);
        const unsigned lo = (unsigned)e;
        const int px = (int)((lo >> 10) & 63);
        if (eu > encThr[px]) continue;               // exact threshold
        const int k  = (int)(lo & 1023);
        const float* crow = cb + (size_t)k * VQ_D;
        float dot = 0.f;
        #pragma unroll
        for (int q = 0; q < 32; ++q) {
            const float4 cv = *(const float4*)(crow + q * 4);
            dot = fmaf(xl[(q * 4 + 0) * 64 + px], cv.x, dot);
            dot = fmaf(xl[(q * 4 + 1) * 64 + px], cv.y, dot);
            dot = fmaf(xl[(q * 4 + 2) * 64 + px], cv.z, dot);
            dot = fmaf(xl[(q * 4 + 3) * 64 + px], cv.w, dot);
        }
        const float t3 = (x2s[px] - 2.0f * dot) + e2[k];
        const unsigned long long key =
            ((unsigned long long)__float_as_uint(t3) << 32) | (unsigned)k;
        atomicMin(&fkey[px], key);
    }
    __syncthreads();

    // ---- writeback: f32x4 nt stores, rows direct from L2-hot cb ----
    {
        const int px4 = (tid & 15) << 2;
        const int dbl = tid >> 4;                    // 0..15
        const float* r0 = cb + (size_t)(unsigned)(fkey[px4 + 0] & 0xFFFFFFFFULL) * VQ_D;
        const float* r1 = cb + (size_t)(unsigned)(fkey[px4 + 1] & 0xFFFFFFFFULL) * VQ_D;
        const float* r2 = cb + (size_t)(unsigned)(fkey[px4 + 2] & 0xFFFFFFFFULL) * VQ_D;
        const float* r3 = cb + (size_t)(unsigned)(fkey[px4 + 3] & 0xFFFFFFFFULL) * VQ_D;
        float* og = out + (size_t)b * VQ_D * VQ_HW + hw0;
        #pragma unroll
        for (int j = 0; j < 8; ++j) {
            const int d = dbl + (j << 4);
            f32x4 v;
            v.x = r0[d]; v.y = r1[d]; v.z = r2[d]; v.w = r3[d];
            __builtin_nontemporal_store(v, (f32x4*)(og + (size_t)d * VQ_HW + px4));
        }
    }
}

extern "C" void kernel_launch(void* const* d_in, const int* in_sizes, int n_in,
                              void* d_out, int out_size, void* d_ws, size_t ws_size,
                              hipStream_t stream) {
    const float* latents = (const float*)d_in[0];
    const float* cb      = (const float*)d_in[1];
    unsigned short* cbbf = (unsigned short*)d_ws;              // 256 KB
    float* e2            = (float*)((char*)d_ws + 262144);     // 4 KB
    float* out           = (float*)d_out;

    vq_prep_kernel<<<dim3(32), dim3(256), 0, stream>>>(cb, cbbf, e2);
    vq_main_kernel<<<dim3(1024), dim3(256), 0, stream>>>(latents, cb, cbbf, e2, out);
}